// Round 16
// baseline (7267.552 us; speedup 1.0000x reference)
//
#include <hip/hip_runtime.h>
#include <cmath>

#define BATCHN 256
#define SEQT   1024
#define EMBED  1024
#define HID    1024
#define VOCABN 32000

typedef __attribute__((ext_vector_type(8))) _Float16 half8;
typedef __attribute__((ext_vector_type(4))) _Float16 half4;
typedef __attribute__((ext_vector_type(4))) float    float4v;
typedef __attribute__((ext_vector_type(4))) unsigned int uint4v;
typedef __attribute__((ext_vector_type(2))) unsigned int uint2v;

#define LOSCALE 4096.0f
#define LOINV   (1.0f/4096.0f)

union FU16 { _Float16 f; unsigned short u; };
__device__ inline unsigned short f16bits(_Float16 f){ FU16 t; t.f=f; return t.u; }
__device__ inline _Float16 bits16(unsigned short u){ FU16 t; t.u=u; return t.f; }

__device__ inline void async16(const void* g, void* l) {
  __builtin_amdgcn_global_load_lds(
      (const __attribute__((address_space(1))) void*)g,
      (__attribute__((address_space(3))) void*)l, 16, 0, 0);
}

// ---------------- f32 -> f16 convert ----------------
__global__ void convert_f32_f16(const float* __restrict__ in,
                                _Float16* __restrict__ out, int n) {
  int i = (blockIdx.x * blockDim.x + threadIdx.x) * 4;
  if (i + 3 < n) {
    float4v v = *reinterpret_cast<const float4v*>(in + i);
    half4 o;
#pragma unroll
    for (int j = 0; j < 4; ++j) o[j] = (_Float16)v[j];
    *reinterpret_cast<half4*>(out + i) = o;
  }
}

// ---------------- f32 -> f16 hi/lo split (lo pre-scaled by 2^12) ----------------
__global__ void split_f32_f16(const float* __restrict__ in,
                              _Float16* __restrict__ hi,
                              _Float16* __restrict__ lo, int n) {
  int i = (blockIdx.x * blockDim.x + threadIdx.x) * 4;
  if (i + 3 < n) {
    float4v v = *reinterpret_cast<const float4v*>(in + i);
    half4 h, l;
#pragma unroll
    for (int j = 0; j < 4; ++j) {
      h[j] = (_Float16)v[j];
      l[j] = (_Float16)((v[j] - (float)h[j]) * LOSCALE);
    }
    *reinterpret_cast<half4*>(hi + i) = h;
    *reinterpret_cast<half4*>(lo + i) = l;
  }
}

// ---------------- Phase 1: xi = emb[x] @ Wi^T + bi  (f16 MFMA, 128x128 tile) ----------------
// xi OUTPUT LAYOUT (scan-order blocks): block (tt, gb, gc) of 2KB:
//   xi[ (tt*256 + gb*16 + gc)*1024 + brow*64 + ncol ]  (halfs)
__global__ __launch_bounds__(256, 2) void gemm_xi(
    const _Float16* __restrict__ embh,  // [VOCAB][1024] f16
    const _Float16* __restrict__ Wih,   // [1024][1024] f16 (n-major, k inner)
    const int* __restrict__ x,          // [256][1024]
    const float* __restrict__ bi,       // [1024]
    _Float16* __restrict__ xi,          // [Tc*256*1024] f16, block layout above
    int t0, int Tc)
{
  __shared__ __align__(16) _Float16 As[128 * 64];
  __shared__ __align__(16) _Float16 Bs[128 * 64];
  __shared__ __align__(16) _Float16 stage[128 * 132];
  __shared__ int toks[128];

  const int tid  = threadIdx.x;
  const int wid  = tid >> 6, lane = tid & 63;
  const int nt   = blockIdx.x & 7, mt = blockIdx.x >> 3;
  const int m0   = mt * 128, n0 = nt * 128;

  if (tid < 128) {
    int m  = m0 + tid;
    int tl = m >> 8;           // local t within chunk
    int b  = m & 255;          // batch row
    toks[tid] = x[b * SEQT + t0 + tl];
  }
  __syncthreads();

  const _Float16* aptr[4];
  const _Float16* bptr[4];
  int ldsoff[4];
#pragma unroll
  for (int i = 0; i < 4; ++i) {
    int idx = i * 256 + tid;
    int row = idx >> 3, kc = idx & 7;
    aptr[i]   = embh + (size_t)toks[row] * 1024 + kc * 8;
    bptr[i]   = Wih + ((size_t)(n0 + row) << 10) + kc * 8;
    ldsoff[i] = idx * 8;  // elements
  }

  float4v acc[4][4] = {};
  const int wm = wid & 1, wn = wid >> 1;
  const int cn = lane & 15, kg = lane >> 4;

  for (int k0 = 0; k0 < 1024; k0 += 64) {
#pragma unroll
    for (int i = 0; i < 4; ++i) {
      async16(aptr[i] + k0, &As[ldsoff[i]]);
      async16(bptr[i] + k0, &Bs[ldsoff[i]]);
    }
    __syncthreads();

    half8 a[4][2], b[4][2];
#pragma unroll
    for (int mf = 0; mf < 4; ++mf)
#pragma unroll
      for (int kf = 0; kf < 2; ++kf)
        a[mf][kf] = *reinterpret_cast<const half8*>(
            &As[(wm * 64 + mf * 16 + cn) * 64 + kf * 32 + kg * 8]);
#pragma unroll
    for (int nf = 0; nf < 4; ++nf)
#pragma unroll
      for (int kf = 0; kf < 2; ++kf)
        b[nf][kf] = *reinterpret_cast<const half8*>(
            &Bs[(wn * 64 + nf * 16 + cn) * 64 + kf * 32 + kg * 8]);

#pragma unroll
    for (int mf = 0; mf < 4; ++mf)
#pragma unroll
      for (int nf = 0; nf < 4; ++nf)
#pragma unroll
        for (int kf = 0; kf < 2; ++kf)
          acc[mf][nf] = __builtin_amdgcn_mfma_f32_16x16x32_f16(
              a[mf][kf], b[nf][kf], acc[mf][nf], 0, 0, 0);
    __syncthreads();
  }

  // epilogue: add bi, stage in LDS, 16B stores into scan-order blocks
#pragma unroll
  for (int nf = 0; nf < 4; ++nf) {
    int n = wn * 64 + nf * 16 + cn;
    float biv = bi[n0 + n];
#pragma unroll
    for (int mf = 0; mf < 4; ++mf) {
#pragma unroll
      for (int j = 0; j < 4; ++j) {
        int m = wm * 64 + mf * 16 + kg * 4 + j;
        stage[m * 132 + n] = (_Float16)(acc[mf][nf][j] + biv);
      }
    }
  }
  __syncthreads();
#pragma unroll
  for (int p = 0; p < 8; ++p) {
    int chunk = p * 256 + tid;
    int r = chunk >> 4, cc = chunk & 15;
    half4 v0 = *reinterpret_cast<const half4*>(stage + r * 132 + cc * 8);
    half4 v1 = *reinterpret_cast<const half4*>(stage + r * 132 + cc * 8 + 4);
    half8 o;
#pragma unroll
    for (int e = 0; e < 4; ++e) { o[e] = v0[e]; o[4 + e] = v1[e]; }
    int m  = m0 + r;                 // tt*256 + b
    int tt = m >> 8, b = m & 255;
    int n  = n0 + cc * 8;
    size_t addr = ((size_t)(tt * 256 + (b >> 4) * 16 + (n >> 6)) << 10)
                + (size_t)((b & 15) * 64 + (n & 63));
    *reinterpret_cast<half8*>(xi + addr) = o;
  }
}

// ---------------- Phase 2: persistent scan, TWO-PIPELINE (batch-pair) ----------------
// 128 WGs = 8 batch-pairs x 16 col-groups. Each WG runs two independent 16-row
// pipelines A (group 2*gb2) and B (group 2*gb2+1), phase-interleaved so each
// pipeline's LLC sync chain hides under the other's compute. Per-pipeline
// protocol is byte-identical to the proven r12/r15 one: sc0sc1 fence-free ops,
// per-WG flag lines, LDS-counter publish, per-wave 4-flag poll, depth-2 parity
// buffers (disjoint block regions per group). Weights shared (256 AGPRs).
__global__ __launch_bounds__(256, 1) void rnn_scan(
    const _Float16* __restrict__ Whig,   // [1024][1024] f16 (n-major)
    const _Float16* __restrict__ Wlog,   // [1024][1024] f16 residual * 2^12
    const float* __restrict__ bh,        // [1024]
    const _Float16* __restrict__ xi,     // block layout (see gemm_xi)
    float* __restrict__ hstate,          // [256][1024] f32
    float* __restrict__ out,             // [256][1024] f32
    _Float16* __restrict__ hexHi0, _Float16* __restrict__ hexLo0,  // h(t), t even
    _Float16* __restrict__ hexHi1, _Float16* __restrict__ hexLo1,  // h(t), t odd
    int* __restrict__ bar,               // [256 lines][32 ints] flag lines (128B)
    int t0, int Tc)
{
  __shared__ __align__(16) _Float16 HhiA[16 * 1024];
  __shared__ __align__(16) _Float16 HloA[16 * 1024];
  __shared__ __align__(16) _Float16 HhiB[16 * 1024];
  __shared__ __align__(16) _Float16 HloB[16 * 1024];
  __shared__ __align__(16) float    part[4][16][68];  // shared, write/bar/read/bar
  __shared__ int wcntA, wcntB;

  const int tid  = threadIdx.x;
  const int wv   = tid >> 6, lane = tid & 63;
  const int cn   = lane & 15, kg = lane >> 4;
  const int gb2  = blockIdx.x >> 4;     // batch pair (0..7)
  const int gc   = blockIdx.x & 15;     // col group (64 cols)
  const int gA   = gb2 * 2, gB = gb2 * 2 + 1;
  const int r0A  = gA * 16, r0B = gB * 16;
  const int rowl = lane & 15;
  const int cib  = wv * 16 + ((lane >> 4) << 2);
  const int gcol = gc * 64 + cib;
  const size_t baseA = ((size_t)(gA * 16 + gc)) << 10;
  const size_t baseB = ((size_t)(gB * 16 + gc)) << 10;

  // ---- Wh K-slice -> AGPRs (shared by both pipelines) ----
  half8 whi[32], wlo[32];
#pragma unroll
  for (int c = 0; c < 4; ++c)
#pragma unroll
    for (int kkl = 0; kkl < 8; ++kkl) {
      int col = gc * 64 + c * 16 + cn;
      int k   = (wv * 8 + kkl) * 32 + kg * 8;
      whi[c * 8 + kkl] = *reinterpret_cast<const half8*>(Whig + ((size_t)col << 10) + k);
      wlo[c * 8 + kkl] = *reinterpret_cast<const half8*>(Wlog + ((size_t)col << 10) + k);
    }
  const float4v bh4 = *reinterpret_cast<const float4v*>(bh + gcol);

  if (tid == 0) { wcntA = 0; wcntB = 0; }

  // ---- init both LDS h-tiles (swizzle: byte ^= (row&7)<<4) ----
#pragma unroll
  for (int pl = 0; pl < 2; ++pl) {
    _Float16* TH = pl ? HhiB : HhiA;
    _Float16* TL = pl ? HloB : HloA;
    int rbase = pl ? r0B : r0A;
    if (t0 == 0) {
#pragma unroll
      for (int p = 0; p < 8; ++p) {
        int idx = p * 256 + tid, row = idx >> 7, cc = idx & 127;
        int bo = (((row << 11) + cc * 16) ^ ((row & 7) << 4));
        half8 z = {0, 0, 0, 0, 0, 0, 0, 0};
        *reinterpret_cast<half8*>(reinterpret_cast<char*>(TH) + bo) = z;
        *reinterpret_cast<half8*>(reinterpret_cast<char*>(TL) + bo) = z;
      }
    } else {
#pragma unroll
      for (int p = 0; p < 8; ++p) {
        int idx = p * 256 + tid, row = idx >> 7, cc = idx & 127;
        const float* hp = hstate + (((size_t)(rbase + row)) << 10) + cc * 8;
        half8 vh, vl;
#pragma unroll
        for (int e = 0; e < 8; ++e) {
          float f = hp[e];
          _Float16 hi = (_Float16)f;
          vh[e] = hi;
          vl[e] = (_Float16)((f - (float)hi) * LOSCALE);
        }
        int bo = (((row << 11) + cc * 16) ^ ((row & 7) << 4));
        *reinterpret_cast<half8*>(reinterpret_cast<char*>(TH) + bo) = vh;
        *reinterpret_cast<half8*>(reinterpret_cast<char*>(TL) + bo) = vl;
      }
    }
  }
  __syncthreads();

  // xi prologue loads (step 0 for both pipelines)
  uint2v xrA, xrB;
  {
    unsigned long long apA = (unsigned long long)(xi + baseA + (size_t)(rowl * 64 + cib));
    unsigned long long apB = (unsigned long long)(xi + baseB + (size_t)(rowl * 64 + cib));
    asm volatile("global_load_dwordx2 %0, %1, off" : "=v"(xrA) : "v"(apA) : "memory");
    asm volatile("global_load_dwordx2 %0, %1, off" : "=v"(xrB) : "v"(apB) : "memory");
  }
  asm volatile("s_waitcnt vmcnt(0)" ::: "memory");

  uint4v uAh[8], uAl[8], uBh[8], uBl[8];

#define EXCH_ISSUE(SH, SL, G16, UH, UL)                                         \
  _Pragma("unroll")                                                             \
  for (int p = 0; p < 8; ++p) {                                                 \
    int gcb = wv * 4 + (p >> 1), chn = (p & 1) * 64 + lane;                     \
    int rw = chn >> 3, c8 = chn & 7;                                            \
    size_t off = (((size_t)((G16) + gcb)) << 10) + (size_t)(rw * 64 + c8 * 8);  \
    asm volatile("global_load_dwordx4 %0, %1, off sc0 sc1"                      \
                 : "=v"(UH[p]) : "v"((unsigned long long)((SH) + off)) : "memory"); \
    asm volatile("global_load_dwordx4 %0, %1, off sc0 sc1"                      \
                 : "=v"(UL[p]) : "v"((unsigned long long)((SL) + off)) : "memory"); \
  }

#define EXCH_LAND(HHI, HLO, UH, UL)                                             \
  _Pragma("unroll")                                                             \
  for (int p = 0; p < 8; ++p) {                                                 \
    int gcb = wv * 4 + (p >> 1), chn = (p & 1) * 64 + lane;                     \
    int rw = chn >> 3, c8 = chn & 7;                                            \
    int bo = (((rw << 11) + gcb * 128 + c8 * 16) ^ ((rw & 7) << 4));            \
    *reinterpret_cast<uint4v*>(reinterpret_cast<char*>(HHI) + bo) = UH[p];      \
    *reinterpret_cast<uint4v*>(reinterpret_cast<char*>(HLO) + bo) = UL[p];      \
  }                                                                             \
  asm volatile("s_waitcnt lgkmcnt(0)" ::: "memory");                            \
  __builtin_amdgcn_sched_barrier(0);

#define MFMA_ALL(HHI, HLO)                                                      \
  _Pragma("unroll")                                                             \
  for (int kkl = 0; kkl < 8; ++kkl) {                                           \
    int ab = (((cn << 11) + (wv * 8 + kkl) * 64 + kg * 16) ^ ((cn & 7) << 4));  \
    half8 ah = *reinterpret_cast<const half8*>(reinterpret_cast<const char*>(HHI) + ab); \
    half8 al = *reinterpret_cast<const half8*>(reinterpret_cast<const char*>(HLO) + ab); \
    _Pragma("unroll")                                                           \
    for (int c = 0; c < 4; ++c) {                                               \
      asm("v_mfma_f32_16x16x32_f16 %0, %1, %2, %0" : "+v"(ac1[c]) : "v"(ah), "a"(whi[c * 8 + kkl])); \
      asm("v_mfma_f32_16x16x32_f16 %0, %1, %2, %0" : "+v"(ac2[c]) : "v"(al), "a"(whi[c * 8 + kkl])); \
      asm("v_mfma_f32_16x16x32_f16 %0, %1, %2, %0" : "+v"(ac3[c]) : "v"(ah), "a"(wlo[c * 8 + kkl])); \
    }                                                                           \
  }

#define POLL4(G16, TGT)                                                         \
  if (lane < 4) {                                                               \
    const int* fp = bar + ((G16) + wv * 4 + lane) * 32;                         \
    for (;;) {                                                                  \
      int v;                                                                    \
      asm volatile("global_load_dword %0, %1, off sc0 sc1\n\t"                  \
                   "s_waitcnt vmcnt(0)"                                         \
                   : "=v"(v) : "v"((unsigned long long)fp) : "memory");         \
      if (v >= (TGT)) break;                                                    \
      __builtin_amdgcn_s_sleep(1);                                              \
    }                                                                           \
  }

#define PART_REDUCE(VS)                                                         \
  _Pragma("unroll")                                                             \
  for (int c = 0; c < 4; ++c)                                                   \
    _Pragma("unroll")                                                           \
    for (int j = 0; j < 4; ++j)                                                 \
      part[wv][kg * 4 + j][c * 16 + cn] = ac1[c][j] + (ac2[c][j] + ac3[c][j]) * LOINV; \
  asm volatile("s_waitcnt lgkmcnt(0)" ::: "memory");                            \
  __builtin_amdgcn_sched_barrier(0);                                            \
  __builtin_amdgcn_s_barrier();                                                 \
  _Pragma("unroll")                                                             \
  for (int w = 0; w < 4; ++w) {                                                 \
    float4v pw = *reinterpret_cast<const float4v*>(&part[w][rowl][cib]);        \
    _Pragma("unroll")                                                           \
    for (int j = 0; j < 4; ++j) VS[j] += pw[j];                                 \
  }                                                                             \
  asm volatile("s_waitcnt lgkmcnt(0)" ::: "memory");                            \
  __builtin_amdgcn_sched_barrier(0);                                            \
  __builtin_amdgcn_s_barrier();

#define EPILOGUE(VS, XR, BASE, R0)                                              \
  float hv[4];                                                                  \
  unsigned short hu[4], lu[4];                                                  \
  _Pragma("unroll")                                                             \
  for (int cj = 0; cj < 4; ++cj) {                                              \
    unsigned int w = (cj < 2) ? XR[0] : XR[1];                                  \
    unsigned short xb = (cj & 1) ? (unsigned short)(w >> 16) : (unsigned short)(w & 0xffffu); \
    float v = VS[cj] + bh4[cj] + (float)bits16(xb);                             \
    float ex = __expf(2.0f * v);                                                \
    float h  = 1.0f - 2.0f / (ex + 1.0f);                                       \
    hv[cj] = h;                                                                 \
    FU16 thi, tlo;                                                              \
    thi.f = (_Float16)h;                                                        \
    tlo.f = (_Float16)((h - (float)thi.f) * LOSCALE);                           \
    hu[cj] = thi.u; lu[cj] = tlo.u;                                             \
  }                                                                             \
  if (tt < Tc - 1) {                                                            \
    uint2v ph, pl;                                                              \
    ph[0] = (unsigned int)hu[0] | ((unsigned int)hu[1] << 16);                  \
    ph[1] = (unsigned int)hu[2] | ((unsigned int)hu[3] << 16);                  \
    pl[0] = (unsigned int)lu[0] | ((unsigned int)lu[1] << 16);                  \
    pl[1] = (unsigned int)lu[2] | ((unsigned int)lu[3] << 16);                  \
    size_t off = (BASE) + (size_t)(rowl * 64 + cib);                            \
    asm volatile("global_store_dwordx2 %0, %1, off sc0 sc1"                     \
                 :: "v"((unsigned long long)(WHi + off)), "v"(ph) : "memory");  \
    asm volatile("global_store_dwordx2 %0, %1, off sc0 sc1"                     \
                 :: "v"((unsigned long long)(WLo + off)), "v"(pl) : "memory");  \
  }                                                                             \
  if (tglob == SEQT - 1) {                                                      \
    float4v o = {hv[0], hv[1], hv[2], hv[3]};                                   \
    *reinterpret_cast<float4v*>(out + (((size_t)((R0) + rowl)) << 10) + gcol) = o; \
  } else if (tt == Tc - 1) {                                                    \
    float4v o = {hv[0], hv[1], hv[2], hv[3]};                                   \
    *reinterpret_cast<float4v*>(hstate + (((size_t)((R0) + rowl)) << 10) + gcol) = o; \
  }

  for (int tt = 0; tt < Tc; ++tt) {
    const int tglob = t0 + tt;
    const int parW  = (tt + 1) & 1;                       // h(tt+1) buffer pair
    _Float16* WHi = parW ? hexHi1 : hexHi0;
    _Float16* WLo = parW ? hexLo1 : hexLo0;
    const _Float16* RHiT  = (tt & 1) ? hexHi1 : hexHi0;   // h(tt) source
    const _Float16* RLoT  = (tt & 1) ? hexLo1 : hexLo0;

    // ================= PHASE A (step tt of pipeline A) =================
    if (tt != 0) { EXCH_LAND(HhiA, HloA, uAh, uAl) }
    float4v ac1[4] = {}, ac2[4] = {}, ac3[4] = {};
    MFMA_ALL(HhiA, HloA)
    asm volatile("s_nop 7\n\ts_nop 7");

    // B prep: poll B's producers (flag >= tt) and issue B's h(tt) exchange
    if (tt != 0) {
      POLL4(gB * 16, tt)
      EXCH_ISSUE(RHiT, RLoT, gB * 16, uBh, uBl)
    }

    float4v vsA = {};
    PART_REDUCE(vsA)
    { EPILOGUE(vsA, xrA, baseA, r0A) }

    asm volatile("s_waitcnt vmcnt(0)" ::: "memory");      // drain A stores (+B exch)
    if (tt < Tc - 1) {
      if (lane == 0) {
        int old = __hip_atomic_fetch_add(&wcntA, 1, __ATOMIC_RELAXED,
                                         __HIP_MEMORY_SCOPE_WORKGROUP);
        if (old == 4 * tt + 3)
          asm volatile("global_store_dword %0, %1, off sc0 sc1"
                       :: "v"((unsigned long long)(bar + (gA * 16 + gc) * 32)),
                          "v"(tt + 1) : "memory");
      }
      unsigned long long ap = (unsigned long long)
          (xi + baseA + (((size_t)(tt + 1)) << 18) + (size_t)(rowl * 64 + cib));
      asm volatile("global_load_dwordx2 %0, %1, off" : "=v"(xrA) : "v"(ap) : "memory");
    }

    // ================= PHASE B (step tt of pipeline B) =================
    if (tt != 0) { EXCH_LAND(HhiB, HloB, uBh, uBl) }
    {
      float4v bc1[4] = {}, bc2[4] = {}, bc3[4] = {};
#define ac1 bc1
#define ac2 bc2
#define ac3 bc3
      MFMA_ALL(HhiB, HloB)
      asm volatile("s_nop 7\n\ts_nop 7");

      // A prep: poll A's producers (flag >= tt+1) and issue A's h(tt+1) exchange
      if (tt < Tc - 1) {
        POLL4(gA * 16, tt + 1)
        const _Float16* RHiN = parW ? hexHi1 : hexHi0;
        const _Float16* RLoN = parW ? hexLo1 : hexLo0;
        EXCH_ISSUE(RHiN, RLoN, gA * 16, uAh, uAl)
      }

      float4v vsB = {};
      PART_REDUCE(vsB)
      { EPILOGUE(vsB, xrB, baseB, r0B) }
#undef ac1
#undef ac2
#undef ac3
    }

    asm volatile("s_waitcnt vmcnt(0)" ::: "memory");      // drain B stores (+A exch)
    if (tt < Tc - 1) {
      if (lane == 0) {
        int old = __hip_atomic_fetch_add(&wcntB, 1, __ATOMIC_RELAXED,
                                         __HIP_MEMORY_SCOPE_WORKGROUP);
        if (old == 4 * tt + 3)
          asm volatile("global_store_dword %0, %1, off sc0 sc1"
                       :: "v"((unsigned long long)(bar + (gB * 16 + gc) * 32)),
                          "v"(tt + 1) : "memory");
      }
      unsigned long long ap = (unsigned long long)
          (xi + baseB + (((size_t)(tt + 1)) << 18) + (size_t)(rowl * 64 + cib));
      asm volatile("global_load_dwordx2 %0, %1, off" : "=v"(xrB) : "v"(ap) : "memory");
    } else {
      break;
    }
  }
#undef EXCH_ISSUE
#undef EXCH_LAND
#undef MFMA_ALL
#undef POLL4
#undef PART_REDUCE
#undef EPILOGUE
}

extern "C" void kernel_launch(void* const* d_in, const int* in_sizes, int n_in,
                              void* d_out, int out_size, void* d_ws, size_t ws_size,
                              hipStream_t stream) {
  const int*   x   = (const int*)  d_in[0];
  const float* emb = (const float*)d_in[1];
  const float* Wi  = (const float*)d_in[2];
  const float* bi  = (const float*)d_in[3];
  const float* Wh  = (const float*)d_in[4];
  const float* bh  = (const float*)d_in[5];
  float* out = (float*)d_out;

  char* ws = (char*)d_ws;
  size_t off = 0;
  auto alloc = [&](size_t bytes) -> void* {
    void* p = ws + off;
    off = (off + bytes + 255) & ~(size_t)255;
    return p;
  };

  _Float16* embh   = (_Float16*)alloc((size_t)VOCABN * EMBED * 2);
  _Float16* Wih    = (_Float16*)alloc((size_t)HID * EMBED * 2);
  _Float16* Whih   = (_Float16*)alloc((size_t)HID * HID * 2);
  _Float16* Wloh   = (_Float16*)alloc((size_t)HID * HID * 2);
  float*    hstate = (float*)   alloc((size_t)BATCHN * HID * 4);
  _Float16* hexHi0 = (_Float16*)alloc((size_t)BATCHN * HID * 2);
  _Float16* hexLo0 = (_Float16*)alloc((size_t)BATCHN * HID * 2);
  _Float16* hexHi1 = (_Float16*)alloc((size_t)BATCHN * HID * 2);
  _Float16* hexLo1 = (_Float16*)alloc((size_t)BATCHN * HID * 2);
  int* bar  = (int*)alloc(256 * 32 * 4);   // 128B flag line per (group,gc)
  size_t fixed = off;

  // largest power-of-two T-chunk whose xi buffer fits in remaining ws
  int Tc = 1024;
  while (Tc > 4 && fixed + (size_t)BATCHN * Tc * HID * 2 > ws_size) Tc >>= 1;
  _Float16* xih = (_Float16*)alloc((size_t)BATCHN * Tc * HID * 2);

  {
    int n = VOCABN * EMBED;
    convert_f32_f16<<<n / 1024, 256, 0, stream>>>(emb, embh, n);
    n = HID * EMBED;
    convert_f32_f16<<<n / 1024, 256, 0, stream>>>(Wi, Wih, n);
    n = HID * HID;
    split_f32_f16<<<n / 1024, 256, 0, stream>>>(Wh, Whih, Wloh, n);
  }

  for (int t0 = 0; t0 < SEQT; t0 += Tc) {
    int grid = (BATCHN * Tc / 128) * 8;  // 128x128 tiles over [256*Tc, 1024]
    gemm_xi<<<grid, 256, 0, stream>>>(embh, Wih, x, bi, xih, t0, Tc);
    hipMemsetAsync(bar, 0, 256 * 32 * 4, stream);
    rnn_scan<<<128, 256, 0, stream>>>(Whih, Wloh, bh, xih, hstate, out,
                                      hexHi0, hexLo0, hexHi1, hexLo1, bar, t0, Tc);
  }
}

// Round 17
// 5020.954 us; speedup vs baseline: 1.4474x; 1.4474x over previous
//
#include <hip/hip_runtime.h>
#include <cmath>

#define BATCHN 256
#define SEQT   1024
#define EMBED  1024
#define HID    1024
#define VOCABN 32000

typedef __attribute__((ext_vector_type(8))) _Float16 half8;
typedef __attribute__((ext_vector_type(4))) _Float16 half4;
typedef __attribute__((ext_vector_type(4))) float    float4v;
typedef __attribute__((ext_vector_type(4))) unsigned int uint4v;

#define LOSCALE 4096.0f
#define LOINV   (1.0f/4096.0f)

union FU16 { _Float16 f; unsigned short u; };
__device__ inline unsigned short f16bits(_Float16 f){ FU16 t; t.f=f; return t.u; }
__device__ inline _Float16 bits16(unsigned short u){ FU16 t; t.u=u; return t.f; }

__device__ inline void async16(const void* g, void* l) {
  __builtin_amdgcn_global_load_lds(
      (const __attribute__((address_space(1))) void*)g,
      (__attribute__((address_space(3))) void*)l, 16, 0, 0);
}

// ---------------- f32 -> f16 convert ----------------
__global__ void convert_f32_f16(const float* __restrict__ in,
                                _Float16* __restrict__ out, int n) {
  int i = (blockIdx.x * blockDim.x + threadIdx.x) * 4;
  if (i + 3 < n) {
    float4v v = *reinterpret_cast<const float4v*>(in + i);
    half4 o;
#pragma unroll
    for (int j = 0; j < 4; ++j) o[j] = (_Float16)v[j];
    *reinterpret_cast<half4*>(out + i) = o;
  }
}

// ---------------- f32 -> f16 hi/lo split (lo pre-scaled by 2^12) ----------------
__global__ void split_f32_f16(const float* __restrict__ in,
                              _Float16* __restrict__ hi,
                              _Float16* __restrict__ lo, int n) {
  int i = (blockIdx.x * blockDim.x + threadIdx.x) * 4;
  if (i + 3 < n) {
    float4v v = *reinterpret_cast<const float4v*>(in + i);
    half4 h, l;
#pragma unroll
    for (int j = 0; j < 4; ++j) {
      h[j] = (_Float16)v[j];
      l[j] = (_Float16)((v[j] - (float)h[j]) * LOSCALE);
    }
    *reinterpret_cast<half4*>(hi + i) = h;
    *reinterpret_cast<half4*>(lo + i) = l;
  }
}

// ---------------- Phase 1: xi = emb[x] @ Wi^T + bi  (f16 MFMA, 128x128 tile) ----------------
// xi OUTPUT LAYOUT (scan-order blocks): block (tt, gb, gc) of 2KB:
//   xi[ (tt*256 + gb*16 + gc)*1024 + brow*64 + ncol ]  (halfs)
__global__ __launch_bounds__(256, 2) void gemm_xi(
    const _Float16* __restrict__ embh,  // [VOCAB][1024] f16
    const _Float16* __restrict__ Wih,   // [1024][1024] f16 (n-major, k inner)
    const int* __restrict__ x,          // [256][1024]
    const float* __restrict__ bi,       // [1024]
    _Float16* __restrict__ xi,          // [Tc*256*1024] f16, block layout above
    int t0, int Tc)
{
  __shared__ __align__(16) _Float16 As[128 * 64];
  __shared__ __align__(16) _Float16 Bs[128 * 64];
  __shared__ __align__(16) _Float16 stage[128 * 132];
  __shared__ int toks[128];

  const int tid  = threadIdx.x;
  const int wid  = tid >> 6, lane = tid & 63;
  const int nt   = blockIdx.x & 7, mt = blockIdx.x >> 3;
  const int m0   = mt * 128, n0 = nt * 128;

  if (tid < 128) {
    int m  = m0 + tid;
    int tl = m >> 8;           // local t within chunk
    int b  = m & 255;          // batch row
    toks[tid] = x[b * SEQT + t0 + tl];
  }
  __syncthreads();

  const _Float16* aptr[4];
  const _Float16* bptr[4];
  int ldsoff[4];
#pragma unroll
  for (int i = 0; i < 4; ++i) {
    int idx = i * 256 + tid;
    int row = idx >> 3, kc = idx & 7;
    aptr[i]   = embh + (size_t)toks[row] * 1024 + kc * 8;
    bptr[i]   = Wih + ((size_t)(n0 + row) << 10) + kc * 8;
    ldsoff[i] = idx * 8;  // elements
  }

  float4v acc[4][4] = {};
  const int wm = wid & 1, wn = wid >> 1;
  const int cn = lane & 15, kg = lane >> 4;

  for (int k0 = 0; k0 < 1024; k0 += 64) {
#pragma unroll
    for (int i = 0; i < 4; ++i) {
      async16(aptr[i] + k0, &As[ldsoff[i]]);
      async16(bptr[i] + k0, &Bs[ldsoff[i]]);
    }
    __syncthreads();

    half8 a[4][2], b[4][2];
#pragma unroll
    for (int mf = 0; mf < 4; ++mf)
#pragma unroll
      for (int kf = 0; kf < 2; ++kf)
        a[mf][kf] = *reinterpret_cast<const half8*>(
            &As[(wm * 64 + mf * 16 + cn) * 64 + kf * 32 + kg * 8]);
#pragma unroll
    for (int nf = 0; nf < 4; ++nf)
#pragma unroll
      for (int kf = 0; kf < 2; ++kf)
        b[nf][kf] = *reinterpret_cast<const half8*>(
            &Bs[(wn * 64 + nf * 16 + cn) * 64 + kf * 32 + kg * 8]);

#pragma unroll
    for (int mf = 0; mf < 4; ++mf)
#pragma unroll
      for (int nf = 0; nf < 4; ++nf)
#pragma unroll
        for (int kf = 0; kf < 2; ++kf)
          acc[mf][nf] = __builtin_amdgcn_mfma_f32_16x16x32_f16(
              a[mf][kf], b[nf][kf], acc[mf][nf], 0, 0, 0);
    __syncthreads();
  }

  // epilogue: add bi, stage in LDS, 16B stores into scan-order blocks
#pragma unroll
  for (int nf = 0; nf < 4; ++nf) {
    int n = wn * 64 + nf * 16 + cn;
    float biv = bi[n0 + n];
#pragma unroll
    for (int mf = 0; mf < 4; ++mf) {
#pragma unroll
      for (int j = 0; j < 4; ++j) {
        int m = wm * 64 + mf * 16 + kg * 4 + j;
        stage[m * 132 + n] = (_Float16)(acc[mf][nf][j] + biv);
      }
    }
  }
  __syncthreads();
#pragma unroll
  for (int p = 0; p < 8; ++p) {
    int chunk = p * 256 + tid;
    int r = chunk >> 4, cc = chunk & 15;
    half4 v0 = *reinterpret_cast<const half4*>(stage + r * 132 + cc * 8);
    half4 v1 = *reinterpret_cast<const half4*>(stage + r * 132 + cc * 8 + 4);
    half8 o;
#pragma unroll
    for (int e = 0; e < 4; ++e) { o[e] = v0[e]; o[4 + e] = v1[e]; }
    int m  = m0 + r;                 // tt*256 + b
    int tt = m >> 8, b = m & 255;
    int n  = n0 + cc * 8;
    size_t addr = ((size_t)(tt * 256 + (b >> 4) * 16 + (n >> 6)) << 10)
                + (size_t)((b & 15) * 64 + (n & 63));
    *reinterpret_cast<half8*>(xi + addr) = o;
  }
}

// ---------------- Phase 2: persistent scan, 256 WGs = 16 batch-groups x 16 col-groups ----
// K-SPLIT over waves: wave wv covers kk in [wv*8, wv*8+8) for ALL 64 output cols.
// Weights (hi/lo) for that slice live in 256 AGPRs (MFMA "a" operands, r10-proven).
// Each wave reads only its 256-col slice of h from LDS (4x less LDS BW) and the
// exchange is wave-private (no mid-exchange barriers). Partial sums reduced via
// padded LDS. Inter-WG protocol identical to round 11 (fence-free sc0sc1 flags).
__global__ __launch_bounds__(256, 1) void rnn_scan(
    const _Float16* __restrict__ Whig,   // [1024][1024] f16 (n-major)
    const _Float16* __restrict__ Wlog,   // [1024][1024] f16 residual * 2^12
    const float* __restrict__ bh,        // [1024]
    const _Float16* __restrict__ xi,     // block layout (see gemm_xi)
    float* __restrict__ hstate,          // [256][1024] f32
    float* __restrict__ out,             // [256][1024] f32
    _Float16* __restrict__ hexHiA,       // [256 blk][16 row][64 col] f16
    _Float16* __restrict__ hexLoA,
    _Float16* __restrict__ hexHiB,
    _Float16* __restrict__ hexLoB,
    int* __restrict__ bar,               // [256 WGs][32 ints] flag lines (128B each)
    int t0, int Tc)
{
  __shared__ __align__(16) _Float16 Ahi[16 * 1024];
  __shared__ __align__(16) _Float16 Alo[16 * 1024];
  __shared__ __align__(16) float    part[4 * 64 * 20];  // [wave][col64][16 +4 pad]

  const int tid  = threadIdx.x;
  const int wv   = tid >> 6, lane = tid & 63;
  const int cn   = lane & 15, kg = lane >> 4;
  const int gb   = blockIdx.x >> 4;     // batch group (16 rows)
  const int gc   = blockIdx.x & 15;     // col group (64 cols)
  const int r0   = gb * 16;
  const int wcol = gc * 64 + wv * 16 + cn;  // this lane's OUTPUT column (epilogue role)

  // ---- Wh K-slice -> AGPRs: fragment (coltile c, kkl): cols gc*64+c*16+cn,
  //      k = (wv*8+kkl)*32 + kg*8 .. +8. 32 half8 hi + 32 lo = 256 AGPRs.
  half8 whi[32], wlo[32];
#pragma unroll
  for (int c = 0; c < 4; ++c)
#pragma unroll
    for (int kkl = 0; kkl < 8; ++kkl) {
      int col = gc * 64 + c * 16 + cn;
      int k   = (wv * 8 + kkl) * 32 + kg * 8;
      whi[c * 8 + kkl] = *reinterpret_cast<const half8*>(Whig + ((size_t)col << 10) + k);
      wlo[c * 8 + kkl] = *reinterpret_cast<const half8*>(Wlog + ((size_t)col << 10) + k);
    }
  const float bhv = bh[wcol];

  // per-step xi block base offset for this thread (halfs)
  const size_t xibase = ((size_t)(gb * 16 + gc) << 10) + wv * 16 + cn;

  // ---- init LDS h-tile (swizzle: byte ^= (row&7)<<4) ----
  if (t0 == 0) {
#pragma unroll
    for (int p = 0; p < 8; ++p) {
      int idx = p * 256 + tid, row = idx >> 7, cc = idx & 127;
      int bo = (((row << 11) + cc * 16) ^ ((row & 7) << 4));
      half8 z = {0, 0, 0, 0, 0, 0, 0, 0};
      *reinterpret_cast<half8*>(reinterpret_cast<char*>(Ahi) + bo) = z;
      *reinterpret_cast<half8*>(reinterpret_cast<char*>(Alo) + bo) = z;
    }
  } else {
#pragma unroll
    for (int p = 0; p < 8; ++p) {
      int idx = p * 256 + tid, row = idx >> 7, cc = idx & 127;
      const float* hp = hstate + (((size_t)(r0 + row)) << 10) + cc * 8;
      half8 vh, vl;
#pragma unroll
      for (int e = 0; e < 8; ++e) {
        float f = hp[e];
        _Float16 hi = (_Float16)f;
        vh[e] = hi;
        vl[e] = (_Float16)((f - (float)hi) * LOSCALE);
      }
      int bo = (((row << 11) + cc * 16) ^ ((row & 7) << 4));
      *reinterpret_cast<half8*>(reinterpret_cast<char*>(Ahi) + bo) = vh;
      *reinterpret_cast<half8*>(reinterpret_cast<char*>(Alo) + bo) = vl;
    }
  }
  __syncthreads();

  // xi prefetch for step 0
  unsigned int xr[4];
#pragma unroll
  for (int j = 0; j < 4; ++j) {
    unsigned long long ap = (unsigned long long)(xi + xibase + (size_t)(kg * 4 + j) * 64);
    asm volatile("global_load_ushort %0, %1, off" : "=v"(xr[j]) : "v"(ap) : "memory");
  }

  uint4v u1h[4], u1l[4];   // second half of wave's exchange slice, pending in regs

#define MFMA_Q(K0, K1)                                                          \
  _Pragma("unroll")                                                             \
  for (int kkl = (K0); kkl < (K1); ++kkl) {                                     \
    int ab = (((cn << 11) + (wv * 8 + kkl) * 64 + kg * 16) ^ ((cn & 7) << 4));  \
    half8 ah = *reinterpret_cast<const half8*>(reinterpret_cast<const char*>(Ahi) + ab); \
    half8 al = *reinterpret_cast<const half8*>(reinterpret_cast<const char*>(Alo) + ab); \
    _Pragma("unroll")                                                           \
    for (int c = 0; c < 4; ++c) {                                               \
      asm("v_mfma_f32_16x16x32_f16 %0, %1, %2, %0" : "+v"(ac1[c]) : "v"(ah), "a"(whi[c * 8 + kkl])); \
      asm("v_mfma_f32_16x16x32_f16 %0, %1, %2, %0" : "+v"(ac2[c]) : "v"(al), "a"(whi[c * 8 + kkl])); \
      asm("v_mfma_f32_16x16x32_f16 %0, %1, %2, %0" : "+v"(ac3[c]) : "v"(ah), "a"(wlo[c * 8 + kkl])); \
    }                                                                           \
  }

  for (int tt = 0; tt < Tc; ++tt) {
    float4v ac1[4] = {}, ac2[4] = {}, ac3[4] = {};

    // ---- MFMA kkl 0..3 (cols wv*256 .. wv*256+127; LDS written pre-loop) ----
    MFMA_Q(0, 4)

    // ---- wave-private: land second half of exchange slice (loads flew under MFMA) ----
    if (tt != 0) {
      asm volatile("s_waitcnt vmcnt(0)" ::: "memory");
      __builtin_amdgcn_sched_barrier(0);
#pragma unroll
      for (int p = 0; p < 4; ++p) {
        int gcbl = 2 + (p >> 1), ch = (p & 1) * 64 + lane;
        int rowl = ch >> 3, c8 = ch & 7;
        int gcb  = wv * 4 + gcbl;
        int bo = (((rowl << 11) + gcb * 128 + c8 * 16) ^ ((rowl & 7) << 4));
        *reinterpret_cast<uint4v*>(reinterpret_cast<char*>(Ahi) + bo) = u1h[p];
        *reinterpret_cast<uint4v*>(reinterpret_cast<char*>(Alo) + bo) = u1l[p];
      }
      asm volatile("s_waitcnt lgkmcnt(0)" ::: "memory");
      __builtin_amdgcn_sched_barrier(0);
    }

    // ---- MFMA kkl 4..7 ----
    MFMA_Q(4, 8)
    asm volatile("s_nop 7\n\ts_nop 7");   // MFMA -> VALU acc-read hazard

    // ---- combine + partial write to LDS ----
#pragma unroll
    for (int c = 0; c < 4; ++c) {
      float4v pv;
#pragma unroll
      for (int j = 0; j < 4; ++j)
        pv[j] = ac1[c][j] + (ac2[c][j] + ac3[c][j]) * LOINV;
      *reinterpret_cast<float4v*>(&part[(wv * 64 + c * 16 + cn) * 20 + kg * 4]) = pv;
    }
    __syncthreads();

    // ---- reduce 4 waves' partials (owner role: col wcol, rows kg*4+j) ----
    float4v vs = {};
#pragma unroll
    for (int w = 0; w < 4; ++w) {
      float4v pw = *reinterpret_cast<const float4v*>(
          &part[(w * 64 + wv * 16 + cn) * 20 + kg * 4]);
#pragma unroll
      for (int j = 0; j < 4; ++j) vs[j] += pw[j];
    }
    asm volatile("s_waitcnt vmcnt(0)" ::: "memory");  // xi arrived (free in steady state)

    // ---- epilogue ----
    const int tglob = t0 + tt;
    const int par = (tt + 1) & 1;
    _Float16* WHi = par ? hexHiA : hexHiB;
    _Float16* WLo = par ? hexLoA : hexLoB;
#pragma unroll
    for (int j = 0; j < 4; ++j) {
      int rowl = kg * 4 + j;
      int row  = r0 + rowl;
      float v = vs[j] + bhv + (float)bits16((unsigned short)xr[j]);
      float ex = __expf(2.0f * v);
      float h  = 1.0f - 2.0f / (ex + 1.0f);
      if (tt < Tc - 1) {
        FU16 thi, tlo;
        thi.f = (_Float16)h;
        tlo.f = (_Float16)((h - (float)thi.f) * LOSCALE);
        size_t off = (((size_t)(gb * 16 + gc)) << 10) + rowl * 64 + wv * 16 + cn;
        asm volatile("global_store_short %0, %1, off sc0 sc1"
                     :: "v"((unsigned long long)(WHi + off)), "v"((unsigned int)thi.u) : "memory");
        asm volatile("global_store_short %0, %1, off sc0 sc1"
                     :: "v"((unsigned long long)(WLo + off)), "v"((unsigned int)tlo.u) : "memory");
      }
      if (tglob == SEQT - 1) out[(((size_t)row) << 10) + wcol] = h;
      else if (tt == Tc - 1) hstate[(((size_t)row) << 10) + wcol] = h;
    }
    if (tt == Tc - 1) break;  // no barrier/exchange after final step of chunk

    // ---- drain h stores, rendezvous, publish flag ----
    asm volatile("s_waitcnt vmcnt(0)" ::: "memory");
    __builtin_amdgcn_s_barrier();
    const int target = tt + 1;
    if (tid == 0)
      asm volatile("global_store_dword %0, %1, off sc0 sc1"
                   :: "v"((unsigned long long)(bar + (gb * 16 + gc) * 32)),
                      "v"(target) : "memory");

    // xi prefetch for step tt+1 (in flight through poll + exchange)
#pragma unroll
    for (int j = 0; j < 4; ++j) {
      unsigned long long ap = (unsigned long long)
          (xi + xibase + (((size_t)(tt + 1)) << 18) + (size_t)(kg * 4 + j) * 64);
      asm volatile("global_load_ushort %0, %1, off" : "=v"(xr[j]) : "v"(ap) : "memory");
    }

    // ---- poll all 16 producer flags (16 lanes in parallel), then gate ----
    if (tid < 16) {
      const int* fp = bar + (gb * 16 + tid) * 32;
      for (;;) {
        int v;
        asm volatile("global_load_dword %0, %1, off sc0 sc1\n\t"
                     "s_waitcnt vmcnt(0)"
                     : "=v"(v) : "v"((unsigned long long)fp) : "memory");
        if (v >= target) break;
        __builtin_amdgcn_s_sleep(1);
      }
    }
    __builtin_amdgcn_s_barrier();

    // ---- wave-private exchange: wave wv loads cols wv*256..+255 (gcb wv*4..wv*4+3) ----
    const _Float16* SHi = par ? hexHiA : hexHiB;
    const _Float16* SLo = par ? hexLoA : hexLoB;
    uint4v u0h[4], u0l[4];
#pragma unroll
    for (int p = 0; p < 4; ++p) {
      int gcbl = p >> 1, ch = (p & 1) * 64 + lane;
      int rowl = ch >> 3, c8 = ch & 7;
      int gcb  = wv * 4 + gcbl;
      size_t off = (((size_t)(gb * 16 + gcb)) << 10) + rowl * 64 + c8 * 8;
      asm volatile("global_load_dwordx4 %0, %1, off sc0 sc1"
                   : "=v"(u0h[p]) : "v"((unsigned long long)(SHi + off)) : "memory");
      asm volatile("global_load_dwordx4 %0, %1, off sc0 sc1"
                   : "=v"(u0l[p]) : "v"((unsigned long long)(SLo + off)) : "memory");
    }
#pragma unroll
    for (int p = 0; p < 4; ++p) {
      int gcbl = 2 + (p >> 1), ch = (p & 1) * 64 + lane;
      int rowl = ch >> 3, c8 = ch & 7;
      int gcb  = wv * 4 + gcbl;
      size_t off = (((size_t)(gb * 16 + gcb)) << 10) + rowl * 64 + c8 * 8;
      asm volatile("global_load_dwordx4 %0, %1, off sc0 sc1"
                   : "=v"(u1h[p]) : "v"((unsigned long long)(SHi + off)) : "memory");
      asm volatile("global_load_dwordx4 %0, %1, off sc0 sc1"
                   : "=v"(u1l[p]) : "v"((unsigned long long)(SLo + off)) : "memory");
    }
    // first 8 loads done; 8 stay in flight across loop top (land before kkl 4..7)
    asm volatile("s_waitcnt vmcnt(8)" ::: "memory");
    __builtin_amdgcn_sched_barrier(0);
#pragma unroll
    for (int p = 0; p < 4; ++p) {
      int gcbl = p >> 1, ch = (p & 1) * 64 + lane;
      int rowl = ch >> 3, c8 = ch & 7;
      int gcb  = wv * 4 + gcbl;
      int bo = (((rowl << 11) + gcb * 128 + c8 * 16) ^ ((rowl & 7) << 4));
      *reinterpret_cast<uint4v*>(reinterpret_cast<char*>(Ahi) + bo) = u0h[p];
      *reinterpret_cast<uint4v*>(reinterpret_cast<char*>(Alo) + bo) = u0l[p];
    }
    asm volatile("s_waitcnt lgkmcnt(0)" ::: "memory");
    __builtin_amdgcn_sched_barrier(0);
    // no barrier: LDS region is wave-private; loop to MFMA kkl 0..3
  }
#undef MFMA_Q
}

extern "C" void kernel_launch(void* const* d_in, const int* in_sizes, int n_in,
                              void* d_out, int out_size, void* d_ws, size_t ws_size,
                              hipStream_t stream) {
  const int*   x   = (const int*)  d_in[0];
  const float* emb = (const float*)d_in[1];
  const float* Wi  = (const float*)d_in[2];
  const float* bi  = (const float*)d_in[3];
  const float* Wh  = (const float*)d_in[4];
  const float* bh  = (const float*)d_in[5];
  float* out = (float*)d_out;

  char* ws = (char*)d_ws;
  size_t off = 0;
  auto alloc = [&](size_t bytes) -> void* {
    void* p = ws + off;
    off = (off + bytes + 255) & ~(size_t)255;
    return p;
  };

  _Float16* embh   = (_Float16*)alloc((size_t)VOCABN * EMBED * 2);
  _Float16* Wih    = (_Float16*)alloc((size_t)HID * EMBED * 2);
  _Float16* Whih   = (_Float16*)alloc((size_t)HID * HID * 2);
  _Float16* Wloh   = (_Float16*)alloc((size_t)HID * HID * 2);
  float*    hstate = (float*)   alloc((size_t)BATCHN * HID * 4);
  _Float16* hexHiA = (_Float16*)alloc((size_t)BATCHN * HID * 2);
  _Float16* hexLoA = (_Float16*)alloc((size_t)BATCHN * HID * 2);
  _Float16* hexHiB = (_Float16*)alloc((size_t)BATCHN * HID * 2);
  _Float16* hexLoB = (_Float16*)alloc((size_t)BATCHN * HID * 2);
  int* bar  = (int*)alloc(256 * 32 * 4);   // 128B flag line per WG
  size_t fixed = off;

  // largest power-of-two T-chunk whose xi buffer fits in remaining ws
  int Tc = 1024;
  while (Tc > 4 && fixed + (size_t)BATCHN * Tc * HID * 2 > ws_size) Tc >>= 1;
  _Float16* xih = (_Float16*)alloc((size_t)BATCHN * Tc * HID * 2);

  {
    int n = VOCABN * EMBED;
    convert_f32_f16<<<n / 1024, 256, 0, stream>>>(emb, embh, n);
    n = HID * EMBED;
    convert_f32_f16<<<n / 1024, 256, 0, stream>>>(Wi, Wih, n);
    n = HID * HID;
    split_f32_f16<<<n / 1024, 256, 0, stream>>>(Wh, Whih, Wloh, n);
  }

  for (int t0 = 0; t0 < SEQT; t0 += Tc) {
    int grid = (BATCHN * Tc / 128) * 8;  // 128x128 tiles over [256*Tc, 1024]
    gemm_xi<<<grid, 256, 0, stream>>>(embh, Wih, x, bi, xih, t0, Tc);
    hipMemsetAsync(bar, 0, 256 * 32 * 4, stream);
    rnn_scan<<<256, 256, 0, stream>>>(Whih, Wloh, bh, xih, hstate, out,
                                      hexHiA, hexLoA, hexHiB, hexLoB, bar, t0, Tc);
  }
}